// Round 9
// baseline (348.093 us; speedup 1.0000x reference)
//
#include <hip/hip_runtime.h>

#define NM    20           // nmax
#define NP1   21
#define PTS   4            // points per block
#define BLK   64           // one wave: 4 points x 16 workers
#define ROWF  882          // floats per point row = 2*(NM+1)^2
#define BLKF  (PTS * ROWF) // 3528 floats per block
#define BLKF4 (BLKF / 4)   // 882 float4 per block

typedef float f32x4 __attribute__((ext_vector_type(4)));
typedef float f32x2 __attribute__((ext_vector_type(2)));

struct Tbl {
    float dprod[NP1];
    float e[NP1];
    float a[NP1][NP1];
    float b[NP1][NP1];
};

constexpr double csqrt_d(double x) {
    double r = x * 0.5 + 0.5;
    for (int i = 0; i < 48; ++i) r = 0.5 * (r + x / r);
    return r;
}

constexpr Tbl make_tbl() {
    Tbl t{};
    const double inv4pi = 0.28209479177387814;
    double dp = inv4pi;
    t.dprod[0] = (float)dp;
    for (int m = 1; m <= NM; ++m) {
        dp *= -csqrt_d((2.0 * m + 1.0) / (2.0 * m));
        t.dprod[m] = (float)dp;
    }
    for (int m = 0; m <= NM; ++m) t.e[m] = (float)csqrt_d(2.0 * m + 3.0);
    for (int m = 0; m <= NM; ++m)
        for (int n = m + 2; n <= NM; ++n) {
            double nn = (double)n * n, mm = (double)m * m;
            t.a[m][n] = (float)csqrt_d((4.0 * nn - 1.0) / (nn - mm));
            t.b[m][n] = (float)csqrt_d((2.0 * n + 1.0) * (n - 1.0 - m) * (n - 1.0 + m) /
                                       ((2.0 * n - 3.0) * (nn - mm)));
        }
    return t;
}

__constant__ Tbl TBL = make_tbl();

__device__ __forceinline__ void sincos_small(float t, float& sn, float& cs) {
    const float t2 = t * t;
    sn = t * (1.0f + t2 * (-1.0f/6.0f + t2 * (1.0f/120.0f + t2 * (-1.0f/5040.0f))));
    cs = 1.0f + t2 * (-0.5f + t2 * (1.0f/24.0f + t2 * (-1.0f/720.0f + t2 * (1.0f/40320.0f))));
}

// R7 structure, templated: REPS identical passes (diagnostic) and NT store flavor.
template<int REPS, bool NT>
__global__ __launch_bounds__(BLK) void sph_k(const float* __restrict__ theta,
                                             const float* __restrict__ phi,
                                             float* __restrict__ out, int npts) {
    __shared__ __align__(16) float sh[PTS][ROWF];
    const int tid = threadIdx.x;
    const int pt  = tid >> 4;
    const int sub = tid & 15;
    const int gpt0 = blockIdx.x * PTS;
    const int gpt  = gpt0 + pt;

    #pragma unroll 1
    for (int rep = 0; rep < REPS; ++rep) {
        __syncthreads();
        if (gpt < npts) {
            float th = theta[gpt];
            float ph = phi[gpt];
            // opaque copies: force full recompute each rep (no cross-rep CSE)
            asm volatile("v_mov_b32 %0, %1" : "=v"(th) : "v"(th));
            asm volatile("v_mov_b32 %0, %1" : "=v"(ph) : "v"(ph));
            float st, ct, s, x;
            sincos_small(th, st, ct);
            sincos_small(ph, s, x);
            float* row = sh[pt];

            auto do_col = [&](int m) {
                float wc = 1.0f, ws = 0.0f;
                float bc = s * ct, bs = s * st;
                int mb = m;
                #pragma unroll
                for (int i = 0; i < 5; ++i) {
                    const float nwc = wc * bc - ws * bs;
                    const float nws = wc * bs + ws * bc;
                    wc = (mb & 1) ? nwc : wc;
                    ws = (mb & 1) ? nws : ws;
                    mb >>= 1;
                    const float t = bc * bc - bs * bs;
                    bs = 2.0f * bc * bs;
                    bc = t;
                }
                const float wcn = (m & 1) ? -wc : wc;
                const float wsn = (m & 1) ?  ws : -ws;

                float qb = 0.0f, qa = TBL.dprod[m];
                int nn = m * (m + 1);
                for (int n = m; n <= NM; ++n) {
                    *reinterpret_cast<float2*>(row + 2 * (nn + m)) = make_float2(qa * wc, qa * ws);
                    if (m > 0)
                        *reinterpret_cast<float2*>(row + 2 * (nn - m)) = make_float2(qa * wcn, qa * wsn);
                    if (n < NM) {
                        const float qn = (n == m) ? TBL.e[m] * x * qa
                                                  : TBL.a[m][n + 1] * x * qa - TBL.b[m][n + 1] * qb;
                        qb = qa; qa = qn;
                    }
                    nn += 2 * (n + 1);
                }
            };
            do_col(sub);
            if (sub <= 4) do_col(20 - sub);
        }
        __syncthreads();

        const long long base = (long long)blockIdx.x * BLKF;
        if (gpt0 + PTS <= npts) {
            const f32x4* __restrict__ src = reinterpret_cast<const f32x4*>(&sh[0][0]);
            f32x4* __restrict__ dst = reinterpret_cast<f32x4*>(out + base);
            #pragma unroll
            for (int k = 0; k < BLKF4 / BLK; ++k) {
                if constexpr (NT) __builtin_nontemporal_store(src[tid + k * BLK], dst + tid + k * BLK);
                else              dst[tid + k * BLK] = src[tid + k * BLK];
            }
            const int j = tid + (BLKF4 / BLK) * BLK;
            if (j < BLKF4) {
                if constexpr (NT) __builtin_nontemporal_store(src[j], dst + j);
                else              dst[j] = src[j];
            }
        } else {
            const int vpts = npts - gpt0;
            const f32x2* __restrict__ src = reinterpret_cast<const f32x2*>(&sh[0][0]);
            f32x2* __restrict__ dst = reinterpret_cast<f32x2*>(out + base);
            for (int j = tid; j < vpts * (ROWF / 2); j += BLK) {
                if constexpr (NT) __builtin_nontemporal_store(src[j], dst + j);
                else              dst[j] = src[j];
            }
        }
        asm volatile("" ::: "memory");
    }
}

extern "C" void kernel_launch(void* const* d_in, const int* in_sizes, int n_in,
                              void* d_out, int out_size, void* d_ws, size_t ws_size,
                              hipStream_t stream) {
    const float* theta = (const float*)d_in[0];
    const float* phi   = (const float*)d_in[1];
    float* out = (float*)d_out;
    const int npts = in_sizes[0];
    const int blocks = (npts + PTS - 1) / PTS;

    // Diagnostic A: x3 reps, nt stores  (~185us -> cracks rocprof top-5)
    sph_k<3, true><<<blocks, BLK, 0, stream>>>(theta, phi, out, npts);
    // Diagnostic B: x3 reps, plain stores (A/B on store flavor, with counters)
    sph_k<3, false><<<blocks, BLK, 0, stream>>>(theta, phi, out, npts);
    // Real pass (correct final output)
    sph_k<1, true><<<blocks, BLK, 0, stream>>>(theta, phi, out, npts);
}

// Round 10
// 55.266 us; speedup vs baseline: 6.2985x; 6.2985x over previous
//
#include <hip/hip_runtime.h>

#define NM    20           // nmax
#define NP1   21
#define PTS   4            // points per block
#define BLK   128          // 2 waves; 32 lanes per point
#define ROWF  882          // floats per point row = 2*(NM+1)^2
#define BLKF  (PTS * ROWF) // 3528 floats per block
#define BLKF4 (BLKF / 4)   // 882 float4 per block

typedef float f32x4 __attribute__((ext_vector_type(4)));
typedef float f32x2 __attribute__((ext_vector_type(2)));

struct Tbl {
    float dprod[NP1];      // INV_SQRT_4PI * prod_{k<=m} (-sqrt((2k+1)/(2k)))  (CS phase)
    float e[NP1];          // sqrt(2m+3)
    float a[NP1][NP1];
    float b[NP1][NP1];
};

constexpr double csqrt_d(double x) {
    double r = x * 0.5 + 0.5;
    for (int i = 0; i < 48; ++i) r = 0.5 * (r + x / r);
    return r;
}

constexpr Tbl make_tbl() {
    Tbl t{};
    const double inv4pi = 0.28209479177387814;
    double dp = inv4pi;
    t.dprod[0] = (float)dp;
    for (int m = 1; m <= NM; ++m) {
        dp *= -csqrt_d((2.0 * m + 1.0) / (2.0 * m));
        t.dprod[m] = (float)dp;
    }
    for (int m = 0; m <= NM; ++m) t.e[m] = (float)csqrt_d(2.0 * m + 3.0);
    for (int m = 0; m <= NM; ++m)
        for (int n = m + 2; n <= NM; ++n) {
            double nn = (double)n * n, mm = (double)m * m;
            t.a[m][n] = (float)csqrt_d((4.0 * nn - 1.0) / (nn - mm));
            t.b[m][n] = (float)csqrt_d((2.0 * n + 1.0) * (n - 1.0 - m) * (n - 1.0 + m) /
                                       ((2.0 * n - 3.0) * (nn - mm)));
        }
    return t;
}

__constant__ Tbl TBL = make_tbl();

// Taylor sin/cos for t in [0,1.5): max err ~1e-6 over [0,1).
__device__ __forceinline__ void sincos_small(float t, float& sn, float& cs) {
    const float t2 = t * t;
    sn = t * (1.0f + t2 * (-1.0f/6.0f + t2 * (1.0f/120.0f + t2 * (-1.0f/5040.0f))));
    cs = 1.0f + t2 * (-0.5f + t2 * (1.0f/24.0f + t2 * (-1.0f/720.0f + t2 * (1.0f/40320.0f))));
}

// 2-wave blocks, 32 lanes/point, one m-column per lane. LDS 14.1KB/block ->
// 11 blocks x 2 waves = 22 waves/CU (69% occupancy; was 26% — the R8-measured
// latency-bound bottleneck). Trig+s^m via binary-exp ladder (R7). Phase 2:
// linear nt b128 copy of the LDS output image.
__global__ __launch_bounds__(BLK) void sph_kernel(const float* __restrict__ theta,
                                                  const float* __restrict__ phi,
                                                  float* __restrict__ out, int npts) {
    __shared__ __align__(16) float sh[PTS][ROWF];
    const int tid = threadIdx.x;
    const int pt  = tid >> 5;          // 0..3: point within block
    const int col = tid & 31;          // m-column (active if <=20)
    const int gpt0 = blockIdx.x * PTS;
    const int gpt  = gpt0 + pt;

    if (gpt < npts && col <= NM) {
        const float th = theta[gpt];
        const float ph = phi[gpt];
        float st, ct, s, x;
        sincos_small(th, st, ct);      // e^{i*theta}
        sincos_small(ph, s, x);        // s = sin(phi), x = cos(phi)
        float* row = sh[pt];
        const int m = col;

        // W = (s*e^{i*th})^m via 5-step binary exponentiation
        float wc = 1.0f, ws = 0.0f;
        float bc = s * ct, bs = s * st;
        int mb = m;
        #pragma unroll
        for (int i = 0; i < 5; ++i) {
            const float nwc = wc * bc - ws * bs;
            const float nws = wc * bs + ws * bc;
            wc = (mb & 1) ? nwc : wc;
            ws = (mb & 1) ? nws : ws;
            mb >>= 1;
            const float t = bc * bc - bs * bs;
            bs = 2.0f * bc * bs;
            bc = t;
        }
        const float wcn = (m & 1) ? -wc : wc;   // -m channel signs pre-applied
        const float wsn = (m & 1) ?  ws : -ws;

        float qb = 0.0f, qa = TBL.dprod[m];     // Q = P / s^m, same recurrence coeffs
        int nn = m * (m + 1);
        for (int n = m; n <= NM; ++n) {
            *reinterpret_cast<float2*>(row + 2 * (nn + m)) = make_float2(qa * wc, qa * ws);
            if (m > 0)
                *reinterpret_cast<float2*>(row + 2 * (nn - m)) = make_float2(qa * wcn, qa * wsn);
            if (n < NM) {
                const float qn = (n == m) ? TBL.e[m] * x * qa
                                          : TBL.a[m][n + 1] * x * qa - TBL.b[m][n + 1] * qb;
                qb = qa; qa = qn;
            }
            nn += 2 * (n + 1);
        }
    }
    __syncthreads();

    // Phase 2: nontemporal b128 stream of the block's contiguous output image.
    const long long base = (long long)blockIdx.x * BLKF;
    if (gpt0 + PTS <= npts) {
        const f32x4* __restrict__ src = reinterpret_cast<const f32x4*>(&sh[0][0]);
        f32x4* __restrict__ dst = reinterpret_cast<f32x4*>(out + base);
        #pragma unroll
        for (int k = 0; k < BLKF4 / BLK; ++k)                  // 6 full sweeps
            __builtin_nontemporal_store(src[tid + k * BLK], dst + tid + k * BLK);
        const int j = tid + (BLKF4 / BLK) * BLK;               // tail: 768..881
        if (j < BLKF4) __builtin_nontemporal_store(src[j], dst + j);
    } else {
        const int vpts = npts - gpt0;
        const f32x2* __restrict__ src = reinterpret_cast<const f32x2*>(&sh[0][0]);
        f32x2* __restrict__ dst = reinterpret_cast<f32x2*>(out + base);
        for (int j = tid; j < vpts * (ROWF / 2); j += BLK)
            __builtin_nontemporal_store(src[j], dst + j);
    }
}

extern "C" void kernel_launch(void* const* d_in, const int* in_sizes, int n_in,
                              void* d_out, int out_size, void* d_ws, size_t ws_size,
                              hipStream_t stream) {
    const float* theta = (const float*)d_in[0];
    const float* phi   = (const float*)d_in[1];
    float* out = (float*)d_out;
    const int npts = in_sizes[0];
    const int blocks = (npts + PTS - 1) / PTS;
    sph_kernel<<<blocks, BLK, 0, stream>>>(theta, phi, out, npts);
}